// Round 1
// baseline (2486.946 us; speedup 1.0000x reference)
//
#include <hip/hip_runtime.h>
#include <cmath>

typedef __attribute__((ext_vector_type(8))) short short8v;
typedef __attribute__((ext_vector_type(4))) float float4v;
typedef unsigned short u16;

__device__ __forceinline__ float b2f(u16 s) {
  union { unsigned u; float f; } v; v.u = ((unsigned)s) << 16; return v.f;
}
__device__ __forceinline__ u16 f2b(float f) {
  union { float f; unsigned u; } v; v.f = f;
  unsigned r = (v.u + 0x7fffu + ((v.u >> 16) & 1u)) >> 16;
  return (u16)r;
}

// ---------------- conversions ----------------
__global__ __launch_bounds__(256) void cvt_w1_kernel(const float* __restrict__ in,
                                                     u16* __restrict__ outb, long n4) {
  long i = (long)blockIdx.x * 256 + threadIdx.x;
  if (i >= n4) return;
  float4 v = ((const float4*)in)[i];
  ushort4 r; r.x = f2b(v.x); r.y = f2b(v.y); r.z = f2b(v.z); r.w = f2b(v.w);
  ((ushort4*)outb)[i] = r;
}

// Wcb[l][n][k] = bf16(Wc[l][k][n])  (transposed per layer for MFMA B-operand)
__global__ __launch_bounds__(256) void cvt_wc_kernel(const float* __restrict__ in,
                                                     u16* __restrict__ outb, int total) {
  int i = blockIdx.x * 256 + threadIdx.x;
  if (i >= total) return;
  int l = i >> 16; int r = i & 65535; int n = r >> 8; int k = r & 255;
  outb[i] = f2b(in[(l << 16) + (k << 8) + n]);
}

// ---------------- CSR build ----------------
__global__ __launch_bounds__(256) void hist_kernel(const int* __restrict__ rows,
                                                   int* __restrict__ cnt, int E) {
  int i = blockIdx.x * 256 + threadIdx.x;
  if (i < E) atomicAdd(&cnt[rows[i]], 1);
}

__global__ __launch_bounds__(1024) void scan_kernel(int* __restrict__ cursor,
                                                    int* __restrict__ rowptr, int n) {
  __shared__ int sd[1024];
  __shared__ int s_carry;
  if (threadIdx.x == 0) s_carry = 0;
  __syncthreads();
  for (int base = 0; base < n; base += 1024) {
    int i = base + threadIdx.x;
    int v = (i < n) ? cursor[i] : 0;
    sd[threadIdx.x] = v;
    __syncthreads();
    for (int offs = 1; offs < 1024; offs <<= 1) {
      int t = (threadIdx.x >= offs) ? sd[threadIdx.x - offs] : 0;
      __syncthreads();
      sd[threadIdx.x] += t;
      __syncthreads();
    }
    int incl = sd[threadIdx.x];
    int carry = s_carry;
    __syncthreads();
    if (i < n) {
      int excl = carry + incl - v;
      rowptr[i] = excl;
      cursor[i] = excl;
    }
    if (threadIdx.x == 1023) s_carry = carry + sd[1023];
    __syncthreads();
  }
  if (threadIdx.x == 0) rowptr[n] = s_carry;
}

__global__ __launch_bounds__(256) void scatter_kernel(const int* __restrict__ rows,
                                                      const int* __restrict__ cols,
                                                      const float* __restrict__ ew,
                                                      int* __restrict__ cursor,
                                                      int* __restrict__ scol,
                                                      float* __restrict__ sw, int E) {
  int i = blockIdx.x * 256 + threadIdx.x;
  if (i >= E) return;
  int p = atomicAdd(&cursor[rows[i]], 1);
  scol[p] = cols[i];
  sw[p] = ew[i];
}

// ---------------- SpMM layer 1 ----------------
// h1 = relu(spmm(W1)); one wave per dest row, lane owns 4 of 256 cols.
__global__ __launch_bounds__(256) void spmm1_b_kernel(const int* __restrict__ rowptr,
                                                      const int* __restrict__ scol,
                                                      const float* __restrict__ sw,
                                                      const u16* __restrict__ Xb,
                                                      u16* __restrict__ out0, int n) {
  int row = blockIdx.x * 4 + (threadIdx.x >> 6);
  if (row >= n) return;
  int lane = threadIdx.x & 63;
  int s = rowptr[row], e = rowptr[row + 1];
  float a0 = 0, a1 = 0, a2 = 0, a3 = 0;
  for (int j = s; j < e; ++j) {
    int c = scol[j];
    float wv = sw[j];
    ushort4 v = *(const ushort4*)(Xb + ((size_t)c << 8) + (lane << 2));
    a0 = fmaf(wv, b2f(v.x), a0); a1 = fmaf(wv, b2f(v.y), a1);
    a2 = fmaf(wv, b2f(v.z), a2); a3 = fmaf(wv, b2f(v.w), a3);
  }
  ushort4 r;
  r.x = f2b(fmaxf(a0, 0.f)); r.y = f2b(fmaxf(a1, 0.f));
  r.z = f2b(fmaxf(a2, 0.f)); r.w = f2b(fmaxf(a3, 0.f));
  *(ushort4*)(out0 + ((size_t)row << 8) + (lane << 2)) = r;
}

__global__ __launch_bounds__(256) void spmm1_f_kernel(const int* __restrict__ rowptr,
                                                      const int* __restrict__ scol,
                                                      const float* __restrict__ sw,
                                                      const float* __restrict__ X,
                                                      u16* __restrict__ out0, int n) {
  int row = blockIdx.x * 4 + (threadIdx.x >> 6);
  if (row >= n) return;
  int lane = threadIdx.x & 63;
  int s = rowptr[row], e = rowptr[row + 1];
  float a0 = 0, a1 = 0, a2 = 0, a3 = 0;
  for (int j = s; j < e; ++j) {
    int c = scol[j];
    float wv = sw[j];
    float4 v = *(const float4*)(X + ((size_t)c << 8) + (lane << 2));
    a0 = fmaf(wv, v.x, a0); a1 = fmaf(wv, v.y, a1);
    a2 = fmaf(wv, v.z, a2); a3 = fmaf(wv, v.w, a3);
  }
  ushort4 r;
  r.x = f2b(fmaxf(a0, 0.f)); r.y = f2b(fmaxf(a1, 0.f));
  r.z = f2b(fmaxf(a2, 0.f)); r.w = f2b(fmaxf(a3, 0.f));
  *(ushort4*)(out0 + ((size_t)row << 8) + (lane << 2)) = r;
}

// ---------------- SpMM + anchor blend ----------------
// support = 0.9*spmm(h) + 0.1*anchor
__global__ __launch_bounds__(256) void spmm_blend_kernel(const int* __restrict__ rowptr,
                                                         const int* __restrict__ scol,
                                                         const float* __restrict__ sw,
                                                         const u16* __restrict__ Xb,
                                                         const u16* __restrict__ anchor,
                                                         u16* __restrict__ outb, int n) {
  int row = blockIdx.x * 4 + (threadIdx.x >> 6);
  if (row >= n) return;
  int lane = threadIdx.x & 63;
  int s = rowptr[row], e = rowptr[row + 1];
  float a0 = 0, a1 = 0, a2 = 0, a3 = 0;
  for (int j = s; j < e; ++j) {
    int c = scol[j];
    float wv = sw[j];
    ushort4 v = *(const ushort4*)(Xb + ((size_t)c << 8) + (lane << 2));
    a0 = fmaf(wv, b2f(v.x), a0); a1 = fmaf(wv, b2f(v.y), a1);
    a2 = fmaf(wv, b2f(v.z), a2); a3 = fmaf(wv, b2f(v.w), a3);
  }
  size_t o = ((size_t)row << 8) + (lane << 2);
  ushort4 an = *(const ushort4*)(anchor + o);
  ushort4 r;
  r.x = f2b(0.9f * a0 + 0.1f * b2f(an.x));
  r.y = f2b(0.9f * a1 + 0.1f * b2f(an.y));
  r.z = f2b(0.9f * a2 + 0.1f * b2f(an.z));
  r.w = f2b(0.9f * a3 + 0.1f * b2f(an.w));
  *(ushort4*)(outb + o) = r;
}

// ---------------- dense GEMM with fused epilogue ----------------
// Hout = relu(theta*(A@Wc) + (1-theta)*A), A:[M,256] bf16, B:[n][k] (Wc^T) bf16
__global__ __launch_bounds__(256) void gemm_kernel(const u16* __restrict__ A,
                                                   const u16* __restrict__ B,
                                                   u16* __restrict__ Hout,
                                                   int M, float theta) {
  int wave = threadIdx.x >> 6;
  int lane = threadIdx.x & 63;
  int m0 = blockIdx.x * 64 + wave * 16;
  if (m0 >= M) return;  // M % 16 == 0, frags all-or-nothing valid
  int arow = m0 + (lane & 15);
  int khalf = (lane >> 4) * 8;  // 0,8,16,24
  const u16* Aptr = A + (size_t)arow * 256 + khalf;
  int bcol_off = ((lane & 15) << 8) + khalf;

  float4v acc[16];
#pragma unroll
  for (int i = 0; i < 16; ++i) acc[i] = (float4v){0.f, 0.f, 0.f, 0.f};

  for (int ks = 0; ks < 8; ++ks) {
    short8v a = *(const short8v*)(Aptr + ks * 32);
#pragma unroll
    for (int nf = 0; nf < 16; ++nf) {
      short8v b = *(const short8v*)(B + (nf << 12) + bcol_off + ks * 32);
      acc[nf] = __builtin_amdgcn_mfma_f32_16x16x32_bf16(a, b, acc[nf], 0, 0, 0);
    }
  }

  int crow_base = m0 + (lane >> 4) * 4;
  int ccol = lane & 15;
  float omt = 1.0f - theta;
#pragma unroll
  for (int nf = 0; nf < 16; ++nf) {
    int col = nf * 16 + ccol;
#pragma unroll
    for (int j = 0; j < 4; ++j) {
      int r = crow_base + j;
      float sup = b2f(A[(size_t)r * 256 + col]);
      float v = theta * acc[nf][j] + omt * sup;
      Hout[(size_t)r * 256 + col] = f2b(fmaxf(v, 0.f));
    }
  }
}

// ---------------- h @ W2 (256 -> 10) ----------------
__global__ __launch_bounds__(256) void gemm2_kernel(const u16* __restrict__ Hb,
                                                    const float* __restrict__ W2,
                                                    float* __restrict__ g, int M) {
  int idx = blockIdx.x * 256 + threadIdx.x;
  if (idx >= M * 10) return;
  int r = idx / 10, c = idx - r * 10;
  const u16* hp = Hb + (size_t)r * 256;
  float acc = 0.f;
  for (int k = 0; k < 256; ++k) acc = fmaf(b2f(hp[k]), W2[k * 10 + c], acc);
  g[idx] = acc;
}

// ---------------- final SpMM on [N,10] ----------------
__global__ __launch_bounds__(256) void spmm_final_kernel(const int* __restrict__ rowptr,
                                                         const int* __restrict__ scol,
                                                         const float* __restrict__ sw,
                                                         const float* __restrict__ g,
                                                         float* __restrict__ out, int n) {
  int row = blockIdx.x * 4 + (threadIdx.x >> 6);
  if (row >= n) return;
  int lane = threadIdx.x & 63;
  int es = lane / 10;
  int c = lane - es * 10;
  int s = rowptr[row], e = rowptr[row + 1];
  float acc = 0.f;
  if (lane < 60) {
    for (int j = s + es; j < e; j += 6)
      acc = fmaf(sw[j], g[(size_t)scol[j] * 10 + c], acc);
  }
  float a0 = acc;
  float t1 = __shfl(a0, lane + 10, 64);
  float t2 = __shfl(a0, lane + 20, 64);
  float t3 = __shfl(a0, lane + 30, 64);
  float t4 = __shfl(a0, lane + 40, 64);
  float t5 = __shfl(a0, lane + 50, 64);
  acc = a0 + t1 + t2 + t3 + t4 + t5;
  if (lane < 10) out[(size_t)row * 10 + lane] = acc;
}

extern "C" void kernel_launch(void* const* d_in, const int* in_sizes, int n_in,
                              void* d_out, int out_size, void* d_ws, size_t ws_size,
                              hipStream_t stream) {
  const int* rows = (const int*)d_in[1];
  const int* cols = (const int*)d_in[2];
  const float* ew = (const float*)d_in[3];
  const float* W1 = (const float*)d_in[4];
  const float* Wc = (const float*)d_in[5];
  const float* W2 = (const float*)d_in[6];
  float* out = (float*)d_out;
  const int N = in_sizes[0];
  const int E = in_sizes[1];
  const int L = in_sizes[5] >> 16;  // Wc elements / 65536

  char* w = (char*)d_ws;
  size_t off = 0;
  auto carve = [&](size_t bytes) -> char* {
    char* p = w + off;
    off = (off + bytes + 255) & ~(size_t)255;
    return p;
  };
  int* rowptr = (int*)carve(((size_t)N + 1) * 4);
  int* cursor = (int*)carve((size_t)N * 4);
  int* scol = (int*)carve((size_t)E * 4);
  float* sw = (float*)carve((size_t)E * 4);
  u16* Wcb = (u16*)carve((size_t)L * 65536 * 2);
  u16* layer0 = (u16*)carve((size_t)N * 512);
  u16* bufA = (u16*)carve((size_t)N * 512);
  u16* bufB = (u16*)carve((size_t)N * 512);
  u16* suppt = (u16*)carve((size_t)N * 512);
  float* g = (float*)carve((size_t)N * 40);
  bool useW1b = (off + (size_t)N * 512) <= ws_size;
  u16* W1b = useW1b ? (u16*)carve((size_t)N * 512) : nullptr;

  int nb_rows4 = (N + 3) / 4;
  int nb_E = (E + 255) / 256;

  // CSR build
  (void)hipMemsetAsync(cursor, 0, (size_t)N * 4, stream);
  hist_kernel<<<nb_E, 256, 0, stream>>>(rows, cursor, E);
  scan_kernel<<<1, 1024, 0, stream>>>(cursor, rowptr, N);
  scatter_kernel<<<nb_E, 256, 0, stream>>>(rows, cols, ew, cursor, scol, sw, E);

  // weight conversions
  cvt_wc_kernel<<<(L * 65536 + 255) / 256, 256, 0, stream>>>(Wc, Wcb, L * 65536);
  if (useW1b) {
    long n4 = (long)N * 64;
    cvt_w1_kernel<<<(int)((n4 + 255) / 256), 256, 0, stream>>>(W1, W1b, n4);
    spmm1_b_kernel<<<nb_rows4, 256, 0, stream>>>(rowptr, scol, sw, W1b, layer0, N);
  } else {
    spmm1_f_kernel<<<nb_rows4, 256, 0, stream>>>(rowptr, scol, sw, W1, layer0, N);
  }

  // 8 GCNII layers
  const u16* hin = layer0;
  int half = L / 2;
  for (int i = 0; i < L; ++i) {
    const u16* anchor = (i <= half) ? hin : layer0;
    spmm_blend_kernel<<<nb_rows4, 256, 0, stream>>>(rowptr, scol, sw, hin, anchor, suppt, N);
    u16* hout = (hin == bufA) ? bufB : ((hin == bufB) ? bufA : bufB);
    float theta = logf(0.1f / (float)(i + 1) + 1.0f);
    gemm_kernel<<<(N + 63) / 64, 256, 0, stream>>>(suppt, Wcb + (size_t)i * 65536, hout, N, theta);
    hin = hout;
  }

  // layer2: out = spmm(h @ W2)
  gemm2_kernel<<<(N * 10 + 255) / 256, 256, 0, stream>>>(hin, W2, g, N);
  spmm_final_kernel<<<nb_rows4, 256, 0, stream>>>(rowptr, scol, sw, g, out, N);
}